// Round 9
// baseline (202.873 us; speedup 1.0000x reference)
//
#include <hip/hip_runtime.h>
#include <hip/hip_fp16.h>
#include <math.h>

#define NPG 54
#define EPG 144
#define GLOB 10
#define VROW 216   // V row: 216 embeds only (g fused into out_mlp)

typedef _Float16 f16x8 __attribute__((ext_vector_type(8)));
typedef _Float16 f16x4 __attribute__((ext_vector_type(4)));
typedef _Float16 f16x2 __attribute__((ext_vector_type(2)));
typedef int      i32x2 __attribute__((ext_vector_type(2)));
typedef float    f32x4 __attribute__((ext_vector_type(4)));

// Compiler-only memory fence for same-wave DS ordering (DS pipe is in-order
// per wave -- R5..R8-verified). Cross-wave hazards use __syncthreads().
#define CFENCE() asm volatile("" ::: "memory")

// DPP quad_perm controls (within each 4-lane group)
#define QP_XOR1 0xB1   // [1,0,3,2]
#define QP_XOR2 0x4E   // [2,3,0,1]
__device__ __forceinline__ int dppq(int v, int ctrl_xor2) {
    // constant-folded per call site
    return ctrl_xor2 ? __builtin_amdgcn_update_dpp(0, v, QP_XOR2, 0xF, 0xF, true)
                     : __builtin_amdgcn_update_dpp(0, v, QP_XOR1, 0xF, 0xF, true);
}

// ---------------------------------------------------------------------------
// Kernel 1, round 9: R8 structure (1 graph / 128-thread block, wave w owns
// C-rows 32w..32w+31). Change: lin1's H1T transpose store (8 scalar b16 per
// wave, the last scalar-DS cluster) replaced by an in-register 4x4 fp16
// transpose (DPP quad_perm + v_perm_b32, VALU pipe) + 2 packed b64 stores.
// Within each 4-lane group (lanes 4a..4a+3 of a quad q): lane r holds
// hp[j] = h1[node=16t+4a+r][feat=4q+j]; after transpose lane r holds
// ov[jj] = h1[node=16t+4a+jj][feat=4q+r] -> b64 store H1T[4q+r][16t+4a].
// node>=54 lanes zeroed pre-transpose -> packed store writes the cols 54..63
// zeros explicitly (invariant preserved, no guard).
// ---------------------------------------------------------------------------
struct __align__(16) GL {
    _Float16 Adj[NPG][56];  // 6048 B; overlaid by cat[64][40] after af reads
                            //   cat cols: 0..7 agg1 / 8..15 x  (lin1 K=32)
                            //             0..15 agg2 / 16..31 h1 (lin2 K=32)
    _Float16 H1T[16][88];   // 2816 B, stride 88 halves (176 B, 16B-aligned rows)
                            //   phase A: XT[feat][node]; phase B: h1^T[feat][node]
                            //   cols 54..63 zero (kill k>=54 products)
};

__global__ __launch_bounds__(128, 8) void graph_kernel(
    const float* __restrict__ x,
    const int*   __restrict__ edge_index,
    const float* __restrict__ edge_attr,
    const float* __restrict__ W_rel1, const float* __restrict__ b1,
    const float* __restrict__ W_root1,
    const float* __restrict__ W_rel2, const float* __restrict__ b2,
    const float* __restrict__ W_root2,
    const _Float16* __restrict__ WC,  // packed weights: WC1[16][16] @0, WC2[4][32] @256 (or null)
    _Float16* __restrict__ v_out,     // [B, VROW] fp16
    int E_total)
{
    __shared__ GL L;
    const int tid  = threadIdx.x;
    const int w    = tid >> 6;
    const int lane = tid & 63;
    const int ln15 = lane & 15;
    const int quad = lane >> 4;
    const int g    = blockIdx.x;      // one graph per block
    const int nbase = g * NPG;
    const int ebase = g * EPG;
    const int t0   = 2 * w;           // this wave's t values: t0, t0+1

    _Float16* adjp = &L.Adj[0][0];
    _Float16 (*cat)[40] = (_Float16(*)[40])adjp;   // overlay (rows 0..63)

    // ---- issue global loads FIRST (in flight through zeroing) ----
    // edges: w0 -> e=lane and (lane<16) e=128+lane; w1 -> e=64+lane. All 144.
    const int e0 = (w == 0) ? lane : 64 + lane;
    int   es0 = edge_index[ebase + e0] - nbase;
    int   ed0 = edge_index[(size_t)E_total + ebase + e0] - nbase;
    float ea0 = edge_attr[ebase + e0];
    int es1 = 0, ed1 = -1; float ea1 = 0.0f;
    if (w == 0 && lane < 16) {
        const int e1 = 128 + lane;
        es1 = edge_index[ebase + e1] - nbase;
        ed1 = edge_index[(size_t)E_total + ebase + e1] - nbase;
        ea1 = edge_attr[ebase + e1];
    }
    // x: full wave, one float4/lane: row = w*32+(lane&31), feats half*4..half*4+3
    const int l31  = lane & 31;
    const int halfq = lane >> 5;          // 0: feats 0..3, 1: feats 4..7
    const int xrow = w * 32 + l31;        // node 0..63 across both waves
    f16x4 xq = {0, 0, 0, 0};
    if (xrow < NPG) {
        float4 q = *(const float4*)(x + (size_t)(nbase + xrow) * 8 + halfq * 4);
        xq = (f16x4){ (_Float16)q.x, (_Float16)q.y, (_Float16)q.z, (_Float16)q.w };
    }

    // ---- weight A-fragments (A row = out-feature = ln15) ----
    f16x8 wf1 = {0, 0, 0, 0, 0, 0, 0, 0};
    f16x8 wf2 = {0, 0, 0, 0, 0, 0, 0, 0};
    if (WC) {
        if (quad < 2) wf1 = *(const f16x8*)(WC + ln15 * 16 + quad * 8);
        if (ln15 < 4) wf2 = *(const f16x8*)(WC + 256 + ln15 * 32 + quad * 8);
    } else {
        if (quad == 0) {
            #pragma unroll
            for (int j = 0; j < 8; j++) wf1[j] = (_Float16)W_rel1[j * 16 + ln15];
        } else if (quad == 1) {
            #pragma unroll
            for (int j = 0; j < 8; j++) wf1[j] = (_Float16)W_root1[j * 16 + ln15];
        }
        if (ln15 < 4) {
            #pragma unroll
            for (int j = 0; j < 8; j++) {
                int k = quad * 8 + j;
                wf2[j] = (_Float16)((k < 16) ? W_rel2[k * 4 + ln15]
                                             : W_root2[(k - 16) * 4 + ln15]);
            }
        }
    }
    const float4 b1q = *(const float4*)(b1 + quad * 4);
    const float4 b2q = *(const float4*)b2;

    // ---- phase 0: zero Adj (378 uint4, block-strided); zero H1T[8..15][48..63]
    //      (16 uint4); XT staging rows 0..7 full cols 0..63 (xq=0 pads >=54) ----
    {
        uint4* z = (uint4*)&L;
        #pragma unroll
        for (int i = tid; i < 378; i += 128) z[i] = make_uint4(0, 0, 0, 0);
        if (tid < 16) {
            int r = 8 + (tid >> 1);              // H1T row 8..15
            uint4* z2 = (uint4*)&L.H1T[0][0];
            z2[r * 11 + 6 + (tid & 1)] = make_uint4(0, 0, 0, 0);  // halves 48..63
        }
    }
    #pragma unroll
    for (int f = 0; f < 4; f++) L.H1T[halfq * 4 + f][xrow] = xq[f];
    __syncthreads();   // B1: zeros + XT visible before atomics / reads

    // ---- phase 1: build Adj, one ds_pk_add_f16 per edge (dups sum in HW) ----
    {
        __half2* cell = (__half2*)&L.Adj[ed0][es0 & ~1];
        __half a16 = __float2half(ea0);
        __half z16 = __float2half(0.0f);
        __half2 val = (es0 & 1) ? __halves2half2(z16, a16)
                                : __halves2half2(a16, z16);
        unsafeAtomicAdd(cell, val);
    }
    if (ed1 >= 0) {
        __half2* cell = (__half2*)&L.Adj[ed1][es1 & ~1];
        __half a16 = __float2half(ea1);
        __half z16 = __float2half(0.0f);
        __half2 val = (es1 & 1) ? __halves2half2(z16, a16)
                                : __halves2half2(a16, z16);
        unsafeAtomicAdd(cell, val);
    }
    __syncthreads();   // B2: Adj complete before fragment reads

    // ---- phase 2 (pure reads + MFMA): af for own t-half, xA, conv1 ----
    f16x8 af[2][2];
    #pragma unroll
    for (int tt = 0; tt < 2; tt++)
        #pragma unroll
        for (int c = 0; c < 2; c++)
            af[tt][c] = *(const f16x8*)(adjp + ((t0 + tt) * 16 + ln15) * 56 + c * 32 + quad * 8);
    f16x8 xA[2];
    #pragma unroll
    for (int c = 0; c < 2; c++)
        xA[c] = *(const f16x8*)&L.H1T[ln15][c * 32 + quad * 8];
    f32x4 acc1[2];
    #pragma unroll
    for (int tt = 0; tt < 2; tt++) acc1[tt] = (f32x4){0.f, 0.f, 0.f, 0.f};
    #pragma unroll
    for (int c = 0; c < 2; c++)
        #pragma unroll
        for (int tt = 0; tt < 2; tt++)
            acc1[tt] = __builtin_amdgcn_mfma_f32_16x16x32_f16(xA[c], af[tt][c], acc1[tt], 0, 0, 0);
    __syncthreads();   // B3: ALL phase-2 reads done before ANY overlay store

    // ---- phase 3: overlay stores (own rows only), then lin1 ----
    if (quad < 2) {
        #pragma unroll
        for (int tt = 0; tt < 2; tt++) {
            f16x4 ap;
            #pragma unroll
            for (int r = 0; r < 4; r++) ap[r] = (_Float16)acc1[tt][r];
            *(f16x4*)&cat[(t0 + tt) * 16 + ln15][quad * 4] = ap;
        }
    }
    *(f16x4*)&cat[xrow][8 + halfq * 4] = xq;   // root feats (rows>=54: zeros, discarded)
    CFENCE();          // same-wave RAW: stores above before bc reads below
    f32x4 ci1 = {b1q.x, b1q.y, b1q.z, b1q.w};
    #pragma unroll
    for (int tt = 0; tt < 2; tt++) {
        f16x8 bc = *(const f16x8*)&cat[(t0 + tt) * 16 + ln15][quad * 8];  // k16..31: garbage x wf1=0
        f32x4 hL = __builtin_amdgcn_mfma_f32_16x16x32_f16(wf1, bc, ci1, 0, 0, 0);
        int node = (t0 + tt) * 16 + ln15;
        f16x4 hp;
        #pragma unroll
        for (int r = 0; r < 4; r++) hp[r] = (_Float16)fmaxf(hL[r], 0.0f);
        if (node >= NPG) hp = (f16x4){0, 0, 0, 0};   // zero pre-transpose: keeps
                                                      // H1T cols 54..63 zero below
        *(f16x4*)&cat[node][16 + quad * 4] = hp;      // lin2 B operand (own rows)

        // ---- 4x4 fp16 transpose across the 4-lane group (DPP+perm, VALU) ----
        // in : lane r of group a holds hp[j] = h1[16t+4a+r][4q+j]
        // out: lane r holds ov[jj]         = h1[16t+4a+jj][4q+r]
        {
            int p0 = __builtin_bit_cast(int, (f16x2){hp[0], hp[1]});
            int p1 = __builtin_bit_cast(int, (f16x2){hp[2], hp[3]});
            int X0 = dppq(p0, 1);                 // lane r gets p0 of lane r^2
            int X1 = dppq(p1, 1);                 // lane r gets p1 of lane r^2
            const bool rlo  = (ln15 & 2) == 0;    // r < 2
            const bool rodd = (ln15 & 1) != 0;
            int A = rlo ? p0 : X1;                // A(r): rows 0,1,0',1' pattern
            int B = rlo ? X0 : p1;                // B(r): rows 2,3,2',3'
            int Ax = dppq(A, 0);                  // lane r gets A of lane r^1
            int Bx = dppq(B, 0);
            int o0 = rodd ? (int)__builtin_amdgcn_perm((unsigned)A,  (unsigned)Ax, 0x07060302u)
                          : (int)__builtin_amdgcn_perm((unsigned)Ax, (unsigned)A,  0x05040100u);
            int o1 = rodd ? (int)__builtin_amdgcn_perm((unsigned)B,  (unsigned)Bx, 0x07060302u)
                          : (int)__builtin_amdgcn_perm((unsigned)Bx, (unsigned)B,  0x05040100u);
            f16x4 ov = __builtin_bit_cast(f16x4, (i32x2){o0, o1});
            // packed b64: feat row 4q+r, node base 16t+4a (64 distinct addrs)
            *(f16x4*)&L.H1T[quad * 4 + (ln15 & 3)][(t0 + tt) * 16 + (ln15 & ~3)] = ov;
        }
    }
    __syncthreads();   // B4: both halves' h1^T in H1T before full-width hA reads

    // ---- phase 4: conv2 (hA spans both halves) + lin2, all same-wave after reads ----
    f16x8 hA[2];
    #pragma unroll
    for (int c = 0; c < 2; c++)
        hA[c] = *(const f16x8*)&L.H1T[ln15][c * 32 + quad * 8];
    f32x4 acc2[2];
    #pragma unroll
    for (int tt = 0; tt < 2; tt++) acc2[tt] = (f32x4){0.f, 0.f, 0.f, 0.f};
    #pragma unroll
    for (int c = 0; c < 2; c++)
        #pragma unroll
        for (int tt = 0; tt < 2; tt++)
            acc2[tt] = __builtin_amdgcn_mfma_f32_16x16x32_f16(hA[c], af[tt][c], acc2[tt], 0, 0, 0);
    #pragma unroll
    for (int tt = 0; tt < 2; tt++) {
        f16x4 ap;
        #pragma unroll
        for (int r = 0; r < 4; r++) ap[r] = (_Float16)acc2[tt][r];
        *(f16x4*)&cat[(t0 + tt) * 16 + ln15][quad * 4] = ap;   // agg2, own rows
    }
    CFENCE();          // same-wave RAW: agg2 stores before bv reads
    f32x4 ci2 = {b2q.x, b2q.y, b2q.z, b2q.w};
    #pragma unroll
    for (int tt = 0; tt < 2; tt++) {
        int node = (t0 + tt) * 16 + ln15;
        f16x8 bv = *(const f16x8*)&cat[node][quad * 8];   // 0..15 agg2, 16..31 h1 (own wave)
        f32x4 o = __builtin_amdgcn_mfma_f32_16x16x32_f16(wf2, bv, ci2, 0, 0, 0);
        if (quad == 0 && node < NPG) {
            f16x4 vp;
            #pragma unroll
            for (int r = 0; r < 4; r++) vp[r] = (_Float16)fmaxf(o[r], 0.0f);
            *(f16x4*)(v_out + (size_t)g * VROW + node * 4) = vp;
        }
    }
}

// ---------------------------------------------------------------------------
// Prep kernel: WT = Wo1^T fp16 in Bt's exact [128][BTS] padded layout.
// Block 0 additionally packs WC1[16][16] (wf1 table) and WC2[4][32] (wf2).
// ---------------------------------------------------------------------------
#define BTS 264

__global__ __launch_bounds__(320) void wo1t_prep(
    const float* __restrict__ Wo1,    // [226, 128] fp32
    const float* __restrict__ W_rel1, const float* __restrict__ W_root1,
    const float* __restrict__ W_rel2, const float* __restrict__ W_root2,
    _Float16* __restrict__ WT,        // [128, BTS] fp16
    _Float16* __restrict__ WC)        // [384] fp16: WC1 @0 (256), WC2 @256 (128)
{
    const int n = blockIdx.x;         // 0..127 output row
    const int k = threadIdx.x;        // 0..319
    if (k < BTS) {
        _Float16 v = (_Float16)0.0f;
        if (k < 226) v = (_Float16)Wo1[(size_t)k * 128 + n];
        WT[(size_t)n * BTS + k] = v;  // coalesced write
    }
    if (n == 0) {
        if (k < 256) {   // WC1[row=ln15][kk]: kk<8 W_rel1[kk][row], else W_root1
            int row = k >> 4, kk = k & 15;
            WC[k] = (_Float16)((kk < 8) ? W_rel1[kk * 16 + row]
                                        : W_root1[(kk - 8) * 16 + row]);
        }
        if (k < 128) {   // WC2[row][kk]: kk<16 W_rel2[kk][row], else W_root2
            int row = k >> 5, kk = k & 31;
            WC[256 + k] = (_Float16)((kk < 16) ? W_rel2[kk * 4 + row]
                                               : W_root2[(kk - 16) * 4 + row]);
        }
    }
}

// ---------------------------------------------------------------------------
// Kernel 2: out-MLP via fp16 MFMA; Bt filled by linear int4 copy of WT.
// Unchanged from round 6/7/8 (passed).
// ---------------------------------------------------------------------------
__global__ __launch_bounds__(512) void out_mlp_mfma2(
    const _Float16* __restrict__ V,    // [B, VROW] fp16
    const _Float16* __restrict__ WT,   // [128, BTS] fp16 (pre-transposed Wo1)
    const float* __restrict__ gf,      // [B, 10]
    const float* __restrict__ Wg1, const float* __restrict__ bg1,
    const float* __restrict__ Wg2, const float* __restrict__ bg2,
    const float* __restrict__ Wg3, const float* __restrict__ bg3,
    const float* __restrict__ bo1,
    const float* __restrict__ Wo2,
    const float* __restrict__ bo2,
    float* __restrict__ out)
{
    extern __shared__ _Float16 Bt[];   // [128][BTS] = 67584 B

    const int tid  = threadIdx.x;
    const int w    = tid >> 6;
    const int lane = tid & 63;
    const int ln15 = lane & 15;
    const int quad = lane >> 4;
    const int row0 = blockIdx.x * 128;
    const int row  = row0 + w * 16 + ln15;

    float bo1v[8], wo2v[8];
    #pragma unroll
    for (int t = 0; t < 8; t++) {
        bo1v[t] = bo1[t * 16 + ln15];
        wo2v[t] = Wo2[t * 16 + ln15];
    }
    const float bo2v = bo2[0];

    // ---- per-lane global-MLP for this lane's row (fp32) ----
    float t3[GLOB];
    {
        const float* gr = gf + (size_t)row * GLOB;
        float t0[GLOB];
        #pragma unroll
        for (int i = 0; i < GLOB; i++) t0[i] = gr[i];
        float t1[8];
        #pragma unroll
        for (int j = 0; j < 8; j++) {
            float a = bg1[j];
            #pragma unroll
            for (int i = 0; i < GLOB; i++) a += t0[i] * Wg1[i * 8 + j];
            t1[j] = fmaxf(a, 0.0f);
        }
        float t2[8];
        #pragma unroll
        for (int j = 0; j < 8; j++) {
            float a = bg2[j];
            #pragma unroll
            for (int i = 0; i < 8; i++) a += t1[i] * Wg2[i * 8 + j];
            t2[j] = fmaxf(a, 0.0f);
        }
        #pragma unroll
        for (int j = 0; j < GLOB; j++) {
            float a = bg3[j];
            #pragma unroll
            for (int i = 0; i < 8; i++) a += t2[i] * Wg3[i * GLOB + j];
            t3[j] = fmaxf(a, 0.0f);
        }
    }

    // ---- A-fragments: s<6 from V; s=6 quad3 + s=7 quad0 from g ----
    const _Float16* Arow = V + (size_t)row * VROW;
    f16x8 af[8];
    #pragma unroll
    for (int s = 0; s < 6; s++)
        af[s] = *(const f16x8*)(Arow + s * 32 + quad * 8);
    if (quad == 3)
        af[6] = (f16x8){ (_Float16)t3[0], (_Float16)t3[1], (_Float16)t3[2], (_Float16)t3[3],
                         (_Float16)t3[4], (_Float16)t3[5], (_Float16)t3[6], (_Float16)t3[7] };
    else
        af[6] = *(const f16x8*)(Arow + 192 + quad * 8);
    af[7] = (f16x8){0, 0, 0, 0, 0, 0, 0, 0};
    if (quad == 0) { af[7][0] = (_Float16)t3[8]; af[7][1] = (_Float16)t3[9]; }

    // ---- Bt <- WT: linear int4 copy (conflict-free), 4224 int4 ----
    {
        const int4* wt4 = (const int4*)WT;
        int4* bt4 = (int4*)Bt;
        for (int i = tid; i < 4224; i += 512) bt4[i] = wt4[i];
    }
    __syncthreads();

    f32x4 acc[8];
    #pragma unroll
    for (int t = 0; t < 8; t++) acc[t] = (f32x4){0.f, 0.f, 0.f, 0.f};

    for (int s = 0; s < 8; s++) {
        #pragma unroll
        for (int t = 0; t < 8; t++) {
            f16x8 bf = *(const f16x8*)&Bt[(t * 16 + ln15) * BTS + s * 32 + quad * 8];
            acc[t] = __builtin_amdgcn_mfma_f32_16x16x32_f16(af[s], bf, acc[t], 0, 0, 0);
        }
    }

    #pragma unroll
    for (int rr = 0; rr < 4; rr++) {
        float p = 0.0f;
        #pragma unroll
        for (int t = 0; t < 8; t++) {
            float h = fmaxf(acc[t][rr] + bo1v[t], 0.0f);
            p += h * wo2v[t];
        }
        p += __shfl_xor(p, 1);
        p += __shfl_xor(p, 2);
        p += __shfl_xor(p, 4);
        p += __shfl_xor(p, 8);
        if (ln15 == rr) {
            int orow = row0 + w * 16 + quad * 4 + rr;
            out[orow] = 1.0f / (1.0f + expf(-(p + bo2v)));
        }
    }
}

// ---------------------------------------------------------------------------
// Kernel 2 (fallback, ws too small): original in-kernel staging version.
// ---------------------------------------------------------------------------
__global__ __launch_bounds__(512) void out_mlp_mfma(
    const _Float16* __restrict__ V,
    const float* __restrict__ gf,
    const float* __restrict__ Wg1, const float* __restrict__ bg1,
    const float* __restrict__ Wg2, const float* __restrict__ bg2,
    const float* __restrict__ Wg3, const float* __restrict__ bg3,
    const float* __restrict__ Wo1,
    const float* __restrict__ bo1,
    const float* __restrict__ Wo2,
    const float* __restrict__ bo2,
    float* __restrict__ out)
{
    extern __shared__ _Float16 Bt[];

    const int tid  = threadIdx.x;
    const int w    = tid >> 6;
    const int lane = tid & 63;
    const int ln15 = lane & 15;
    const int quad = lane >> 4;
    const int row0 = blockIdx.x * 128;
    const int row  = row0 + w * 16 + ln15;

    float bo1v[8], wo2v[8];
    #pragma unroll
    for (int t = 0; t < 8; t++) {
        bo1v[t] = bo1[t * 16 + ln15];
        wo2v[t] = Wo2[t * 16 + ln15];
    }
    const float bo2v = bo2[0];

    float t3[GLOB];
    {
        const float* gr = gf + (size_t)row * GLOB;
        float t0[GLOB];
        #pragma unroll
        for (int i = 0; i < GLOB; i++) t0[i] = gr[i];
        float t1[8];
        #pragma unroll
        for (int j = 0; j < 8; j++) {
            float a = bg1[j];
            #pragma unroll
            for (int i = 0; i < GLOB; i++) a += t0[i] * Wg1[i * 8 + j];
            t1[j] = fmaxf(a, 0.0f);
        }
        float t2[8];
        #pragma unroll
        for (int j = 0; j < 8; j++) {
            float a = bg2[j];
            #pragma unroll
            for (int i = 0; i < 8; i++) a += t1[i] * Wg2[i * 8 + j];
            t2[j] = fmaxf(a, 0.0f);
        }
        #pragma unroll
        for (int j = 0; j < GLOB; j++) {
            float a = bg3[j];
            #pragma unroll
            for (int i = 0; i < 8; i++) a += t2[i] * Wg3[i * GLOB + j];
            t3[j] = fmaxf(a, 0.0f);
        }
    }

    const _Float16* Arow = V + (size_t)row * VROW;
    f16x8 af[8];
    #pragma unroll
    for (int s = 0; s < 6; s++)
        af[s] = *(const f16x8*)(Arow + s * 32 + quad * 8);
    if (quad == 3)
        af[6] = (f16x8){ (_Float16)t3[0], (_Float16)t3[1], (_Float16)t3[2], (_Float16)t3[3],
                         (_Float16)t3[4], (_Float16)t3[5], (_Float16)t3[6], (_Float16)t3[7] };
    else
        af[6] = *(const f16x8*)(Arow + 192 + quad * 8);
    af[7] = (f16x8){0, 0, 0, 0, 0, 0, 0, 0};
    if (quad == 0) { af[7][0] = (_Float16)t3[8]; af[7][1] = (_Float16)t3[9]; }

    {
        int4* bz = (int4*)Bt;
        for (int i = tid; i < 4224; i += 512)
            bz[i] = make_int4(0, 0, 0, 0);
    }
    __syncthreads();
    for (int i = tid; i < 7232; i += 512) {
        int k  = i >> 5;
        int nq = (i & 31) * 4;
        float4 v = *(const float4*)(Wo1 + (size_t)k * 128 + nq);
        Bt[(nq + 0) * BTS + k] = (_Float16)v.x;
        Bt[(nq + 1) * BTS + k] = (_Float16)v.y;
        Bt[(nq + 2) * BTS + k] = (_Float16)v.z;
        Bt[(nq + 3) * BTS + k] = (_Float16)v.w;
    }
    __syncthreads();

    f32x4 acc[8];
    #pragma unroll
    for (int t = 0; t < 8; t++) acc[t] = (f32x4){0.f, 0.f, 0.f, 0.f};

    for (int s = 0; s < 8; s++) {
        #pragma unroll
        for (int t = 0; t < 8; t++) {
            f16x8 bf = *(const f16x8*)&Bt[(t * 16 + ln15) * BTS + s * 32 + quad * 8];
            acc[t] = __builtin_amdgcn_mfma_f32_16x16x32_f16(af[s], bf, acc[t], 0, 0, 0);
        }
    }

    #pragma unroll
    for (int rr = 0; rr < 4; rr++) {
        float p = 0.0f;
        #pragma unroll
        for (int t = 0; t < 8; t++) {
            float h = fmaxf(acc[t][rr] + bo1v[t], 0.0f);
            p += h * wo2v[t];
        }
        p += __shfl_xor(p, 1);
        p += __shfl_xor(p, 2);
        p += __shfl_xor(p, 4);
        p += __shfl_xor(p, 8);
        if (ln15 == rr) {
            int orow = row0 + w * 16 + quad * 4 + rr;
            out[orow] = 1.0f / (1.0f + expf(-(p + bo2v)));
        }
    }
}

// ---------------------------------------------------------------------------
extern "C" void kernel_launch(void* const* d_in, const int* in_sizes, int n_in,
                              void* d_out, int out_size, void* d_ws, size_t ws_size,
                              hipStream_t stream) {
    const float* x        = (const float*)d_in[0];
    const int*   ei       = (const int*)  d_in[1];
    const float* ea       = (const float*)d_in[2];
    const float* gf       = (const float*)d_in[3];
    const float* W_rel1   = (const float*)d_in[4];
    const float* b1       = (const float*)d_in[5];
    const float* W_root1  = (const float*)d_in[6];
    const float* W_rel2   = (const float*)d_in[7];
    const float* b2       = (const float*)d_in[8];
    const float* W_root2  = (const float*)d_in[9];
    const float* Wg1      = (const float*)d_in[10];
    const float* bg1      = (const float*)d_in[11];
    const float* Wg2      = (const float*)d_in[12];
    const float* bg2      = (const float*)d_in[13];
    const float* Wg3      = (const float*)d_in[14];
    const float* bg3      = (const float*)d_in[15];
    const float* Wo1      = (const float*)d_in[16];
    const float* bo1      = (const float*)d_in[17];
    const float* Wo2      = (const float*)d_in[18];
    const float* bo2      = (const float*)d_in[19];

    float* out   = (float*)d_out;
    _Float16* V  = (_Float16*)d_ws;             // [B, VROW] fp16

    const int B = out_size;                     // 32768
    const int E = in_sizes[1] / 2;

    const size_t VBYTES  = (size_t)B * VROW * sizeof(_Float16);
    const size_t WTBYTES = (size_t)128 * BTS * sizeof(_Float16);
    const size_t WCBYTES = (size_t)384 * sizeof(_Float16);
    _Float16* WT = (_Float16*)((char*)d_ws + VBYTES);
    _Float16* WC = (_Float16*)((char*)d_ws + VBYTES + WTBYTES);
    const bool use_prep = (ws_size >= VBYTES + WTBYTES + WCBYTES);

    if (use_prep)
        wo1t_prep<<<128, 320, 0, stream>>>(Wo1, W_rel1, W_root1, W_rel2, W_root2, WT, WC);

    graph_kernel<<<B, 128, 0, stream>>>(
        x, ei, ea,
        W_rel1, b1, W_root1, W_rel2, b2, W_root2,
        use_prep ? WC : (const _Float16*)nullptr, V, E);

    if (use_prep)
        out_mlp_mfma2<<<B / 128, 512, 128 * BTS * sizeof(_Float16), stream>>>(
            V, WT, gf, Wg1, bg1, Wg2, bg2, Wg3, bg3, bo1, Wo2, bo2, out);
    else
        out_mlp_mfma<<<B / 128, 512, 128 * BTS * sizeof(_Float16), stream>>>(
            V, gf, Wg1, bg1, Wg2, bg2, Wg3, bg3, Wo1, bo1, Wo2, bo2, out);
}

// Round 10
// 201.110 us; speedup vs baseline: 1.0088x; 1.0088x over previous
//
#include <hip/hip_runtime.h>
#include <hip/hip_fp16.h>
#include <math.h>

#define NPG 54
#define EPG 144
#define GLOB 10
#define VROW 216   // V row: 216 embeds only (g fused into out_mlp)

typedef _Float16 f16x8 __attribute__((ext_vector_type(8)));
typedef _Float16 f16x4 __attribute__((ext_vector_type(4)));
typedef float    f32x4 __attribute__((ext_vector_type(4)));

// Compiler-only memory fence for same-wave DS ordering (DS pipe is in-order
// per wave -- R5..R9-verified). Cross-wave hazards use __syncthreads().
#define CFENCE() asm volatile("" ::: "memory")

// ---------------------------------------------------------------------------
// Kernel 1, round 10: exact revert to the R8 configuration (best measured:
// 58.0 us graph, 202.7 us total). R9's DPP 4x4 transpose replacing lin1's
// 8 scalar b16 H1T stores was a measured net loss (58.0 -> 59.6 us,
// conflicts 4.78M -> 5.31M): those scalar stores are ~2-way banked (free
// tier) and cheaper than the DPP+perm VALU cost plus the packed store's
// added conflicts. Structure: 1 graph / 128-thread block, wave w owns
// C-rows 32w..32w+31; operand-swapped dataflow (C col = node) throughout.
//   conv1: agg1^T = X^T @ Adj^T   (A=XT LDS b128, B=Adj b128 frags)
//   lin1 : h1^T   = Wc1^T @ cat^T (prep-packed wf1 regs as A)
//   conv2: agg2^T = H1T @ Adj^T   (A=H1T b128 rows, B=same Adj frags)
//   lin2 : h2^T   = Wc2^T @ cat^T -> direct packed global V store
// ---------------------------------------------------------------------------
struct __align__(16) GL {
    _Float16 Adj[NPG][56];  // 6048 B; overlaid by cat[64][40] after af reads
                            //   cat cols: 0..7 agg1 / 8..15 x  (lin1 K=32)
                            //             0..15 agg2 / 16..31 h1 (lin2 K=32)
    _Float16 H1T[16][88];   // 2816 B, stride 88 halves (176 B, 16B-aligned rows)
                            //   phase A: XT[feat][node]; phase B: h1^T[feat][node]
                            //   cols 54..63 zero (kill k>=54 products)
};

__global__ __launch_bounds__(128, 8) void graph_kernel(
    const float* __restrict__ x,
    const int*   __restrict__ edge_index,
    const float* __restrict__ edge_attr,
    const float* __restrict__ W_rel1, const float* __restrict__ b1,
    const float* __restrict__ W_root1,
    const float* __restrict__ W_rel2, const float* __restrict__ b2,
    const float* __restrict__ W_root2,
    const _Float16* __restrict__ WC,  // packed weights: WC1[16][16] @0, WC2[4][32] @256 (or null)
    _Float16* __restrict__ v_out,     // [B, VROW] fp16
    int E_total)
{
    __shared__ GL L;
    const int tid  = threadIdx.x;
    const int w    = tid >> 6;
    const int lane = tid & 63;
    const int ln15 = lane & 15;
    const int quad = lane >> 4;
    const int g    = blockIdx.x;      // one graph per block
    const int nbase = g * NPG;
    const int ebase = g * EPG;
    const int t0   = 2 * w;           // this wave's t values: t0, t0+1

    _Float16* adjp = &L.Adj[0][0];
    _Float16 (*cat)[40] = (_Float16(*)[40])adjp;   // overlay (rows 0..63)

    // ---- issue global loads FIRST (in flight through zeroing) ----
    // edges: w0 -> e=lane and (lane<16) e=128+lane; w1 -> e=64+lane. All 144.
    const int e0 = (w == 0) ? lane : 64 + lane;
    int   es0 = edge_index[ebase + e0] - nbase;
    int   ed0 = edge_index[(size_t)E_total + ebase + e0] - nbase;
    float ea0 = edge_attr[ebase + e0];
    int es1 = 0, ed1 = -1; float ea1 = 0.0f;
    if (w == 0 && lane < 16) {
        const int e1 = 128 + lane;
        es1 = edge_index[ebase + e1] - nbase;
        ed1 = edge_index[(size_t)E_total + ebase + e1] - nbase;
        ea1 = edge_attr[ebase + e1];
    }
    // x: full wave, one float4/lane: row = w*32+(lane&31), feats half*4..half*4+3
    const int l31  = lane & 31;
    const int halfq = lane >> 5;          // 0: feats 0..3, 1: feats 4..7
    const int xrow = w * 32 + l31;        // node 0..63 across both waves
    f16x4 xq = {0, 0, 0, 0};
    if (xrow < NPG) {
        float4 q = *(const float4*)(x + (size_t)(nbase + xrow) * 8 + halfq * 4);
        xq = (f16x4){ (_Float16)q.x, (_Float16)q.y, (_Float16)q.z, (_Float16)q.w };
    }

    // ---- weight A-fragments (A row = out-feature = ln15) ----
    f16x8 wf1 = {0, 0, 0, 0, 0, 0, 0, 0};
    f16x8 wf2 = {0, 0, 0, 0, 0, 0, 0, 0};
    if (WC) {
        if (quad < 2) wf1 = *(const f16x8*)(WC + ln15 * 16 + quad * 8);
        if (ln15 < 4) wf2 = *(const f16x8*)(WC + 256 + ln15 * 32 + quad * 8);
    } else {
        if (quad == 0) {
            #pragma unroll
            for (int j = 0; j < 8; j++) wf1[j] = (_Float16)W_rel1[j * 16 + ln15];
        } else if (quad == 1) {
            #pragma unroll
            for (int j = 0; j < 8; j++) wf1[j] = (_Float16)W_root1[j * 16 + ln15];
        }
        if (ln15 < 4) {
            #pragma unroll
            for (int j = 0; j < 8; j++) {
                int k = quad * 8 + j;
                wf2[j] = (_Float16)((k < 16) ? W_rel2[k * 4 + ln15]
                                             : W_root2[(k - 16) * 4 + ln15]);
            }
        }
    }
    const float4 b1q = *(const float4*)(b1 + quad * 4);
    const float4 b2q = *(const float4*)b2;

    // ---- phase 0: zero Adj (378 uint4, block-strided); zero H1T[8..15][48..63]
    //      (16 uint4); XT staging rows 0..7 full cols 0..63 (xq=0 pads >=54) ----
    {
        uint4* z = (uint4*)&L;
        #pragma unroll
        for (int i = tid; i < 378; i += 128) z[i] = make_uint4(0, 0, 0, 0);
        if (tid < 16) {
            int r = 8 + (tid >> 1);              // H1T row 8..15
            uint4* z2 = (uint4*)&L.H1T[0][0];
            z2[r * 11 + 6 + (tid & 1)] = make_uint4(0, 0, 0, 0);  // halves 48..63
        }
    }
    #pragma unroll
    for (int f = 0; f < 4; f++) L.H1T[halfq * 4 + f][xrow] = xq[f];
    __syncthreads();   // B1: zeros + XT visible before atomics / reads

    // ---- phase 1: build Adj, one ds_pk_add_f16 per edge (dups sum in HW) ----
    {
        __half2* cell = (__half2*)&L.Adj[ed0][es0 & ~1];
        __half a16 = __float2half(ea0);
        __half z16 = __float2half(0.0f);
        __half2 val = (es0 & 1) ? __halves2half2(z16, a16)
                                : __halves2half2(a16, z16);
        unsafeAtomicAdd(cell, val);
    }
    if (ed1 >= 0) {
        __half2* cell = (__half2*)&L.Adj[ed1][es1 & ~1];
        __half a16 = __float2half(ea1);
        __half z16 = __float2half(0.0f);
        __half2 val = (es1 & 1) ? __halves2half2(z16, a16)
                                : __halves2half2(a16, z16);
        unsafeAtomicAdd(cell, val);
    }
    __syncthreads();   // B2: Adj complete before fragment reads

    // ---- phase 2 (pure reads + MFMA): af for own t-half, xA, conv1 ----
    //      af[tt][c][m] = Adj[dst=(t0+tt)*16+ln15][src=c*32+quad*8+m]
    //      Row spills (>=54) read XT/garbage (finite); C cols >=54 discarded.
    f16x8 af[2][2];
    #pragma unroll
    for (int tt = 0; tt < 2; tt++)
        #pragma unroll
        for (int c = 0; c < 2; c++)
            af[tt][c] = *(const f16x8*)(adjp + ((t0 + tt) * 16 + ln15) * 56 + c * 32 + quad * 8);
    f16x8 xA[2];
    #pragma unroll
    for (int c = 0; c < 2; c++)
        xA[c] = *(const f16x8*)&L.H1T[ln15][c * 32 + quad * 8];
    f32x4 acc1[2];
    #pragma unroll
    for (int tt = 0; tt < 2; tt++) acc1[tt] = (f32x4){0.f, 0.f, 0.f, 0.f};
    #pragma unroll
    for (int c = 0; c < 2; c++)
        #pragma unroll
        for (int tt = 0; tt < 2; tt++)
            acc1[tt] = __builtin_amdgcn_mfma_f32_16x16x32_f16(xA[c], af[tt][c], acc1[tt], 0, 0, 0);
    __syncthreads();   // B3: ALL phase-2 reads done before ANY overlay store

    // ---- phase 3: overlay stores (own rows only), then lin1 ----
    if (quad < 2) {
        #pragma unroll
        for (int tt = 0; tt < 2; tt++) {
            f16x4 ap;
            #pragma unroll
            for (int r = 0; r < 4; r++) ap[r] = (_Float16)acc1[tt][r];
            *(f16x4*)&cat[(t0 + tt) * 16 + ln15][quad * 4] = ap;
        }
    }
    *(f16x4*)&cat[xrow][8 + halfq * 4] = xq;   // root feats (rows>=54: zeros, discarded)
    CFENCE();          // same-wave RAW: stores above before bc reads below
    f32x4 ci1 = {b1q.x, b1q.y, b1q.z, b1q.w};
    #pragma unroll
    for (int tt = 0; tt < 2; tt++) {
        f16x8 bc = *(const f16x8*)&cat[(t0 + tt) * 16 + ln15][quad * 8];  // k16..31: garbage x wf1=0
        f32x4 hL = __builtin_amdgcn_mfma_f32_16x16x32_f16(wf1, bc, ci1, 0, 0, 0);
        int node = (t0 + tt) * 16 + ln15;
        f16x4 hp;
        #pragma unroll
        for (int r = 0; r < 4; r++) hp[r] = (_Float16)fmaxf(hL[r], 0.0f);
        *(f16x4*)&cat[node][16 + quad * 4] = hp;          // lin2 B operand (own rows)
        if (node < NPG) {                                  // H1T cols 54..63 stay ZERO
            #pragma unroll
            for (int r = 0; r < 4; r++) L.H1T[quad * 4 + r][node] = hp[r];
        }
    }
    __syncthreads();   // B4: both halves' h1^T in H1T before full-width hA reads

    // ---- phase 4: conv2 (hA spans both halves) + lin2, all same-wave after reads ----
    f16x8 hA[2];
    #pragma unroll
    for (int c = 0; c < 2; c++)
        hA[c] = *(const f16x8*)&L.H1T[ln15][c * 32 + quad * 8];
    f32x4 acc2[2];
    #pragma unroll
    for (int tt = 0; tt < 2; tt++) acc2[tt] = (f32x4){0.f, 0.f, 0.f, 0.f};
    #pragma unroll
    for (int c = 0; c < 2; c++)
        #pragma unroll
        for (int tt = 0; tt < 2; tt++)
            acc2[tt] = __builtin_amdgcn_mfma_f32_16x16x32_f16(hA[c], af[tt][c], acc2[tt], 0, 0, 0);
    #pragma unroll
    for (int tt = 0; tt < 2; tt++) {
        f16x4 ap;
        #pragma unroll
        for (int r = 0; r < 4; r++) ap[r] = (_Float16)acc2[tt][r];
        *(f16x4*)&cat[(t0 + tt) * 16 + ln15][quad * 4] = ap;   // agg2, own rows
    }
    CFENCE();          // same-wave RAW: agg2 stores before bv reads
    f32x4 ci2 = {b2q.x, b2q.y, b2q.z, b2q.w};
    #pragma unroll
    for (int tt = 0; tt < 2; tt++) {
        int node = (t0 + tt) * 16 + ln15;
        f16x8 bv = *(const f16x8*)&cat[node][quad * 8];   // 0..15 agg2, 16..31 h1 (own wave)
        f32x4 o = __builtin_amdgcn_mfma_f32_16x16x32_f16(wf2, bv, ci2, 0, 0, 0);
        if (quad == 0 && node < NPG) {
            f16x4 vp;
            #pragma unroll
            for (int r = 0; r < 4; r++) vp[r] = (_Float16)fmaxf(o[r], 0.0f);
            *(f16x4*)(v_out + (size_t)g * VROW + node * 4) = vp;
        }
    }
}

// ---------------------------------------------------------------------------
// Prep kernel: WT = Wo1^T fp16 in Bt's exact [128][BTS] padded layout.
// Block 0 additionally packs WC1[16][16] (wf1 table) and WC2[4][32] (wf2).
// ---------------------------------------------------------------------------
#define BTS 264

__global__ __launch_bounds__(320) void wo1t_prep(
    const float* __restrict__ Wo1,    // [226, 128] fp32
    const float* __restrict__ W_rel1, const float* __restrict__ W_root1,
    const float* __restrict__ W_rel2, const float* __restrict__ W_root2,
    _Float16* __restrict__ WT,        // [128, BTS] fp16
    _Float16* __restrict__ WC)        // [384] fp16: WC1 @0 (256), WC2 @256 (128)
{
    const int n = blockIdx.x;         // 0..127 output row
    const int k = threadIdx.x;        // 0..319
    if (k < BTS) {
        _Float16 v = (_Float16)0.0f;
        if (k < 226) v = (_Float16)Wo1[(size_t)k * 128 + n];
        WT[(size_t)n * BTS + k] = v;  // coalesced write
    }
    if (n == 0) {
        if (k < 256) {   // WC1[row=ln15][kk]: kk<8 W_rel1[kk][row], else W_root1
            int row = k >> 4, kk = k & 15;
            WC[k] = (_Float16)((kk < 8) ? W_rel1[kk * 16 + row]
                                        : W_root1[(kk - 8) * 16 + row]);
        }
        if (k < 128) {   // WC2[row][kk]: kk<16 W_rel2[kk][row], else W_root2
            int row = k >> 5, kk = k & 31;
            WC[256 + k] = (_Float16)((kk < 16) ? W_rel2[kk * 4 + row]
                                               : W_root2[(kk - 16) * 4 + row]);
        }
    }
}

// ---------------------------------------------------------------------------
// Kernel 2: out-MLP via fp16 MFMA; Bt filled by linear int4 copy of WT.
// Unchanged from round 6..9 (passed).
// ---------------------------------------------------------------------------
__global__ __launch_bounds__(512) void out_mlp_mfma2(
    const _Float16* __restrict__ V,    // [B, VROW] fp16
    const _Float16* __restrict__ WT,   // [128, BTS] fp16 (pre-transposed Wo1)
    const float* __restrict__ gf,      // [B, 10]
    const float* __restrict__ Wg1, const float* __restrict__ bg1,
    const float* __restrict__ Wg2, const float* __restrict__ bg2,
    const float* __restrict__ Wg3, const float* __restrict__ bg3,
    const float* __restrict__ bo1,
    const float* __restrict__ Wo2,
    const float* __restrict__ bo2,
    float* __restrict__ out)
{
    extern __shared__ _Float16 Bt[];   // [128][BTS] = 67584 B

    const int tid  = threadIdx.x;
    const int w    = tid >> 6;
    const int lane = tid & 63;
    const int ln15 = lane & 15;
    const int quad = lane >> 4;
    const int row0 = blockIdx.x * 128;
    const int row  = row0 + w * 16 + ln15;

    float bo1v[8], wo2v[8];
    #pragma unroll
    for (int t = 0; t < 8; t++) {
        bo1v[t] = bo1[t * 16 + ln15];
        wo2v[t] = Wo2[t * 16 + ln15];
    }
    const float bo2v = bo2[0];

    // ---- per-lane global-MLP for this lane's row (fp32) ----
    float t3[GLOB];
    {
        const float* gr = gf + (size_t)row * GLOB;
        float t0[GLOB];
        #pragma unroll
        for (int i = 0; i < GLOB; i++) t0[i] = gr[i];
        float t1[8];
        #pragma unroll
        for (int j = 0; j < 8; j++) {
            float a = bg1[j];
            #pragma unroll
            for (int i = 0; i < GLOB; i++) a += t0[i] * Wg1[i * 8 + j];
            t1[j] = fmaxf(a, 0.0f);
        }
        float t2[8];
        #pragma unroll
        for (int j = 0; j < 8; j++) {
            float a = bg2[j];
            #pragma unroll
            for (int i = 0; i < 8; i++) a += t1[i] * Wg2[i * 8 + j];
            t2[j] = fmaxf(a, 0.0f);
        }
        #pragma unroll
        for (int j = 0; j < GLOB; j++) {
            float a = bg3[j];
            #pragma unroll
            for (int i = 0; i < 8; i++) a += t2[i] * Wg3[i * GLOB + j];
            t3[j] = fmaxf(a, 0.0f);
        }
    }

    // ---- A-fragments: s<6 from V; s=6 quad3 + s=7 quad0 from g ----
    const _Float16* Arow = V + (size_t)row * VROW;
    f16x8 af[8];
    #pragma unroll
    for (int s = 0; s < 6; s++)
        af[s] = *(const f16x8*)(Arow + s * 32 + quad * 8);
    if (quad == 3)
        af[6] = (f16x8){ (_Float16)t3[0], (_Float16)t3[1], (_Float16)t3[2], (_Float16)t3[3],
                         (_Float16)t3[4], (_Float16)t3[5], (_Float16)t3[6], (_Float16)t3[7] };
    else
        af[6] = *(const f16x8*)(Arow + 192 + quad * 8);
    af[7] = (f16x8){0, 0, 0, 0, 0, 0, 0, 0};
    if (quad == 0) { af[7][0] = (_Float16)t3[8]; af[7][1] = (_Float16)t3[9]; }

    // ---- Bt <- WT: linear int4 copy (conflict-free), 4224 int4 ----
    {
        const int4* wt4 = (const int4*)WT;
        int4* bt4 = (int4*)Bt;
        for (int i = tid; i < 4224; i += 512) bt4[i] = wt4[i];
    }
    __syncthreads();

    f32x4 acc[8];
    #pragma unroll
    for (int t = 0; t < 8; t++) acc[t] = (f32x4){0.f, 0.f, 0.f, 0.f};

    for (int s = 0; s < 8; s++) {
        #pragma unroll
        for (int t = 0; t < 8; t++) {
            f16x8 bf = *(const f16x8*)&Bt[(t * 16 + ln15) * BTS + s * 32 + quad * 8];
            acc[t] = __builtin_amdgcn_mfma_f32_16x16x32_f16(af[s], bf, acc[t], 0, 0, 0);
        }
    }

    #pragma unroll
    for (int rr = 0; rr < 4; rr++) {
        float p = 0.0f;
        #pragma unroll
        for (int t = 0; t < 8; t++) {
            float h = fmaxf(acc[t][rr] + bo1v[t], 0.0f);
            p += h * wo2v[t];
        }
        p += __shfl_xor(p, 1);
        p += __shfl_xor(p, 2);
        p += __shfl_xor(p, 4);
        p += __shfl_xor(p, 8);
        if (ln15 == rr) {
            int orow = row0 + w * 16 + quad * 4 + rr;
            out[orow] = 1.0f / (1.0f + expf(-(p + bo2v)));
        }
    }
}

// ---------------------------------------------------------------------------
// Kernel 2 (fallback, ws too small): original in-kernel staging version.
// ---------------------------------------------------------------------------
__global__ __launch_bounds__(512) void out_mlp_mfma(
    const _Float16* __restrict__ V,
    const float* __restrict__ gf,
    const float* __restrict__ Wg1, const float* __restrict__ bg1,
    const float* __restrict__ Wg2, const float* __restrict__ bg2,
    const float* __restrict__ Wg3, const float* __restrict__ bg3,
    const float* __restrict__ Wo1,
    const float* __restrict__ bo1,
    const float* __restrict__ Wo2,
    const float* __restrict__ bo2,
    float* __restrict__ out)
{
    extern __shared__ _Float16 Bt[];

    const int tid  = threadIdx.x;
    const int w    = tid >> 6;
    const int lane = tid & 63;
    const int ln15 = lane & 15;
    const int quad = lane >> 4;
    const int row0 = blockIdx.x * 128;
    const int row  = row0 + w * 16 + ln15;

    float bo1v[8], wo2v[8];
    #pragma unroll
    for (int t = 0; t < 8; t++) {
        bo1v[t] = bo1[t * 16 + ln15];
        wo2v[t] = Wo2[t * 16 + ln15];
    }
    const float bo2v = bo2[0];

    float t3[GLOB];
    {
        const float* gr = gf + (size_t)row * GLOB;
        float t0[GLOB];
        #pragma unroll
        for (int i = 0; i < GLOB; i++) t0[i] = gr[i];
        float t1[8];
        #pragma unroll
        for (int j = 0; j < 8; j++) {
            float a = bg1[j];
            #pragma unroll
            for (int i = 0; i < GLOB; i++) a += t0[i] * Wg1[i * 8 + j];
            t1[j] = fmaxf(a, 0.0f);
        }
        float t2[8];
        #pragma unroll
        for (int j = 0; j < 8; j++) {
            float a = bg2[j];
            #pragma unroll
            for (int i = 0; i < 8; i++) a += t1[i] * Wg2[i * 8 + j];
            t2[j] = fmaxf(a, 0.0f);
        }
        #pragma unroll
        for (int j = 0; j < GLOB; j++) {
            float a = bg3[j];
            #pragma unroll
            for (int i = 0; i < 8; i++) a += t2[i] * Wg3[i * GLOB + j];
            t3[j] = fmaxf(a, 0.0f);
        }
    }

    const _Float16* Arow = V + (size_t)row * VROW;
    f16x8 af[8];
    #pragma unroll
    for (int s = 0; s < 6; s++)
        af[s] = *(const f16x8*)(Arow + s * 32 + quad * 8);
    if (quad == 3)
        af[6] = (f16x8){ (_Float16)t3[0], (_Float16)t3[1], (_Float16)t3[2], (_Float16)t3[3],
                         (_Float16)t3[4], (_Float16)t3[5], (_Float16)t3[6], (_Float16)t3[7] };
    else
        af[6] = *(const f16x8*)(Arow + 192 + quad * 8);
    af[7] = (f16x8){0, 0, 0, 0, 0, 0, 0, 0};
    if (quad == 0) { af[7][0] = (_Float16)t3[8]; af[7][1] = (_Float16)t3[9]; }

    {
        int4* bz = (int4*)Bt;
        for (int i = tid; i < 4224; i += 512)
            bz[i] = make_int4(0, 0, 0, 0);
    }
    __syncthreads();
    for (int i = tid; i < 7232; i += 512) {
        int k  = i >> 5;
        int nq = (i & 31) * 4;
        float4 v = *(const float4*)(Wo1 + (size_t)k * 128 + nq);
        Bt[(nq + 0) * BTS + k] = (_Float16)v.x;
        Bt[(nq + 1) * BTS + k] = (_Float16)v.y;
        Bt[(nq + 2) * BTS + k] = (_Float16)v.z;
        Bt[(nq + 3) * BTS + k] = (_Float16)v.w;
    }
    __syncthreads();

    f32x4 acc[8];
    #pragma unroll
    for (int t = 0; t < 8; t++) acc[t] = (f32x4){0.f, 0.f, 0.f, 0.f};

    for (int s = 0; s < 8; s++) {
        #pragma unroll
        for (int t = 0; t < 8; t++) {
            f16x8 bf = *(const f16x8*)&Bt[(t * 16 + ln15) * BTS + s * 32 + quad * 8];
            acc[t] = __builtin_amdgcn_mfma_f32_16x16x32_f16(af[s], bf, acc[t], 0, 0, 0);
        }
    }

    #pragma unroll
    for (int rr = 0; rr < 4; rr++) {
        float p = 0.0f;
        #pragma unroll
        for (int t = 0; t < 8; t++) {
            float h = fmaxf(acc[t][rr] + bo1v[t], 0.0f);
            p += h * wo2v[t];
        }
        p += __shfl_xor(p, 1);
        p += __shfl_xor(p, 2);
        p += __shfl_xor(p, 4);
        p += __shfl_xor(p, 8);
        if (ln15 == rr) {
            int orow = row0 + w * 16 + quad * 4 + rr;
            out[orow] = 1.0f / (1.0f + expf(-(p + bo2v)));
        }
    }
}

// ---------------------------------------------------------------------------
extern "C" void kernel_launch(void* const* d_in, const int* in_sizes, int n_in,
                              void* d_out, int out_size, void* d_ws, size_t ws_size,
                              hipStream_t stream) {
    const float* x        = (const float*)d_in[0];
    const int*   ei       = (const int*)  d_in[1];
    const float* ea       = (const float*)d_in[2];
    const float* gf       = (const float*)d_in[3];
    const float* W_rel1   = (const float*)d_in[4];
    const float* b1       = (const float*)d_in[5];
    const float* W_root1  = (const float*)d_in[6];
    const float* W_rel2   = (const float*)d_in[7];
    const float* b2       = (const float*)d_in[8];
    const float* W_root2  = (const float*)d_in[9];
    const float* Wg1      = (const float*)d_in[10];
    const float* bg1      = (const float*)d_in[11];
    const float* Wg2      = (const float*)d_in[12];
    const float* bg2      = (const float*)d_in[13];
    const float* Wg3      = (const float*)d_in[14];
    const float* bg3      = (const float*)d_in[15];
    const float* Wo1      = (const float*)d_in[16];
    const float* bo1      = (const float*)d_in[17];
    const float* Wo2      = (const float*)d_in[18];
    const float* bo2      = (const float*)d_in[19];

    float* out   = (float*)d_out;
    _Float16* V  = (_Float16*)d_ws;             // [B, VROW] fp16

    const int B = out_size;                     // 32768
    const int E = in_sizes[1] / 2;

    const size_t VBYTES  = (size_t)B * VROW * sizeof(_Float16);
    const size_t WTBYTES = (size_t)128 * BTS * sizeof(_Float16);
    const size_t WCBYTES = (size_t)384 * sizeof(_Float16);
    _Float16* WT = (_Float16*)((char*)d_ws + VBYTES);
    _Float16* WC = (_Float16*)((char*)d_ws + VBYTES + WTBYTES);
    const bool use_prep = (ws_size >= VBYTES + WTBYTES + WCBYTES);

    if (use_prep)
        wo1t_prep<<<128, 320, 0, stream>>>(Wo1, W_rel1, W_root1, W_rel2, W_root2, WT, WC);

    graph_kernel<<<B, 128, 0, stream>>>(
        x, ei, ea,
        W_rel1, b1, W_root1, W_rel2, b2, W_root2,
        use_prep ? WC : (const _Float16*)nullptr, V, E);

    if (use_prep)
        out_mlp_mfma2<<<B / 128, 512, 128 * BTS * sizeof(_Float16), stream>>>(
            V, WT, gf, Wg1, bg1, Wg2, bg2, Wg3, bg3, bo1, Wo2, bo2, out);
    else
        out_mlp_mfma<<<B / 128, 512, 128 * BTS * sizeof(_Float16), stream>>>(
            V, gf, Wg1, bg1, Wg2, bg2, Wg3, bg3, Wo1, bo1, Wo2, bo2, out);
}